// Round 1
// baseline (28846.265 us; speedup 1.0000x reference)
//
#include <hip/hip_runtime.h>

// ---------------- problem constants ----------------
#define T_STEPS 256
#define BATCH   64
#define DIN     512
#define HID     1024
#define NCOLS   4096   // 4*HID
#define NBLK    256    // persistent blocks (1 per CU)
#define TPB     256    // 4 waves

typedef __attribute__((ext_vector_type(8))) short short8;
typedef __attribute__((ext_vector_type(4))) float float4v;

__device__ __forceinline__ short f2bf(float x) {
    unsigned u = __float_as_uint(x);
    u += 0x7FFFu + ((u >> 16) & 1u);   // RNE
    return (short)(u >> 16);
}
__device__ __forceinline__ float sigmoidf_(float x) { return 1.0f / (1.0f + __expf(-x)); }
__device__ __forceinline__ float tanhf_(float x)    { return 1.0f - 2.0f / (__expf(2.0f * x) + 1.0f); }

// ---------------- prologue kernels ----------------
__global__ void cvt_bf16_kernel(const float* __restrict__ src, short* __restrict__ dst, int n) {
    int i = blockIdx.x * blockDim.x + threadIdx.x;
    int stride = gridDim.x * blockDim.x;
    for (; i < n; i += stride) dst[i] = f2bf(src[i]);
}

// src: R x C fp32 row-major -> dst: C x R bf16 row-major
__global__ void transpose_bf16_kernel(const float* __restrict__ src, short* __restrict__ dst,
                                      int R, int C) {
    __shared__ float tile[32][33];
    int tx = threadIdx.x, ty = threadIdx.y;
    int r0 = blockIdx.y * 32, c0 = blockIdx.x * 32;
#pragma unroll
    for (int i = 0; i < 32; i += 8)
        tile[ty + i][tx] = src[(size_t)(r0 + ty + i) * C + (c0 + tx)];
    __syncthreads();
#pragma unroll
    for (int i = 0; i < 32; i += 8)
        dst[(size_t)(c0 + ty + i) * R + (r0 + tx)] = f2bf(tile[tx][ty + i]);
}

// ---------------- grid barrier (256 co-resident blocks) ----------------
__device__ __forceinline__ void grid_barrier(unsigned* cnt, unsigned* gen) {
    __syncthreads();
    if (threadIdx.x == 0) {
        __threadfence();  // release prior writes device-wide
        unsigned g = __hip_atomic_load(gen, __ATOMIC_RELAXED, __HIP_MEMORY_SCOPE_AGENT);
        unsigned old = __hip_atomic_fetch_add(cnt, 1u, __ATOMIC_ACQ_REL, __HIP_MEMORY_SCOPE_AGENT);
        if (old == (unsigned)(NBLK - 1)) {
            __hip_atomic_store(cnt, 0u, __ATOMIC_RELAXED, __HIP_MEMORY_SCOPE_AGENT);
            __hip_atomic_store(gen, g + 1u, __ATOMIC_RELEASE, __HIP_MEMORY_SCOPE_AGENT);
        } else {
            while (__hip_atomic_load(gen, __ATOMIC_ACQUIRE, __HIP_MEMORY_SCOPE_AGENT) == g)
                __builtin_amdgcn_s_sleep(2);
        }
    }
    __syncthreads();
    __threadfence();  // acquire side: see other blocks' writes
}

// ---------------- fused persistent LSTM ----------------
// Block wg owns H-columns [wg*4, wg*4+4) -> s-columns {wg*4+jj + g*1024}.
// wave w computes batch rows [16w,16w+16). MFMA 16x16x32 bf16:
//   A-frag: lane holds A[m=lane&15][k=quad*8+j]  (8 contiguous bf16)
//   B-frag: lane holds B[k=quad*8+j][n=lane&15]
//   D:      lane holds D[row=quad*4+r][col=lane&15], r=0..3
__global__ __launch_bounds__(TPB) void lstm_persist(
    const int* __restrict__ length,
    const float* __restrict__ b0,  const float* __restrict__ g_ih0, const float* __restrict__ bt_ih0,
    const float* __restrict__ g_hh0, const float* __restrict__ bt_hh0,
    const float* __restrict__ g_c0,  const float* __restrict__ bt_c0,
    const float* __restrict__ b1,  const float* __restrict__ g_ih1, const float* __restrict__ bt_ih1,
    const float* __restrict__ g_hh1, const float* __restrict__ bt_hh1,
    const float* __restrict__ g_c1,  const float* __restrict__ bt_c1,
    const short* __restrict__ xb, short* __restrict__ y0b,
    const short* __restrict__ wih0T, const short* __restrict__ whh0T,
    const short* __restrict__ wih1T, const short* __restrict__ whh1T,
    float* __restrict__ h0f, float* __restrict__ c0f,
    float* __restrict__ h1f, float* __restrict__ c1f,
    short* __restrict__ h0b, short* __restrict__ h1b,
    unsigned* bar_cnt, unsigned* bar_gen,
    float* __restrict__ out)
{
    const int wg   = blockIdx.x;
    const int tid  = threadIdx.x;
    const int wave = tid >> 6;
    const int lane = tid & 63;
    const int nidx = lane & 15;
    const int quad = lane >> 4;

    __shared__ float st_s[4][16][17];   // per-wave 16x16 s tile (+pad)
    __shared__ float red_h[4][16][2];   // per-wave column (sum,sumsq) for h@Whh
    __shared__ float red_i[4][16][2];   // ... for x@Wih
    __shared__ float red_c[4][4][2];    // per-wave (sum,sumsq) for c1, 4 j's

    const int jj   = nidx & 3;
    const int gidx = nidx >> 2;
    const int ncol = wg * 4 + jj + gidx * HID;   // s-space column 0..4095
    const int m_row = wave * 16 + nidx;          // A-fragment batch row

    const int mc   = lane & 15;                  // c-phase: row within wave
    const int jc   = quad;                       // c-phase: which of 4 j's
    const int m_cg = wave * 16 + mc;
    const int j_g  = wg * 4 + jc;
    const int len_c = length[m_cg];

    for (int layer = 0; layer < 2; ++layer) {
        const int K = layer ? HID : DIN;
        const int KI = K >> 5;
        const short* xin  = layer ? y0b   : xb;
        const short* wTih = layer ? wih1T : wih0T;
        const short* wThh = layer ? whh1T : whh0T;
        float* hf = layer ? h1f : h0f;
        float* cf = layer ? c1f : c0f;
        short* hb = layer ? h1b : h0b;

        const float gih  = (layer ? g_ih1  : g_ih0 )[ncol];
        const float btih = (layer ? bt_ih1 : bt_ih0)[ncol];
        const float ghh  = (layer ? g_hh1  : g_hh0)[ncol];
        const float bthh = (layer ? bt_hh1 : bt_hh0)[ncol];
        const float bb   = (layer ? b1     : b0   )[ncol];
        const float gc   = (layer ? g_c1   : g_c0 )[j_g];
        const float btc  = (layer ? bt_c1  : bt_c0)[j_g];

        const short8* Bih = (const short8*)wTih + (((size_t)ncol * K) >> 3) + quad;
        const short8* Bhh = (const short8*)wThh + (((size_t)ncol * HID) >> 3) + quad;
        const short8* Ah  = (const short8*)hb + (((size_t)m_row * HID) >> 3) + quad;

        for (int t = 0; t < T_STEPS; ++t) {
            const short8* Ax = (const short8*)xin + (((size_t)(t * BATCH + m_row) * K) >> 3) + quad;
            float4v acc_i = {0.f, 0.f, 0.f, 0.f};
            float4v acc_h = {0.f, 0.f, 0.f, 0.f};
#pragma unroll 8
            for (int kk = 0; kk < KI; ++kk)
                acc_i = __builtin_amdgcn_mfma_f32_16x16x32_bf16(Ax[kk * 4], Bih[kk * 4], acc_i, 0, 0, 0);
#pragma unroll 8
            for (int kk = 0; kk < 32; ++kk)
                acc_h = __builtin_amdgcn_mfma_f32_16x16x32_bf16(Ah[kk * 4], Bhh[kk * 4], acc_h, 0, 0, 0);

            // ---- per-column batch stats (biased var over 64 rows) ----
            float s1h = acc_h[0] + acc_h[1] + acc_h[2] + acc_h[3];
            float s2h = acc_h[0]*acc_h[0] + acc_h[1]*acc_h[1] + acc_h[2]*acc_h[2] + acc_h[3]*acc_h[3];
            float s1i = acc_i[0] + acc_i[1] + acc_i[2] + acc_i[3];
            float s2i = acc_i[0]*acc_i[0] + acc_i[1]*acc_i[1] + acc_i[2]*acc_i[2] + acc_i[3]*acc_i[3];
            s1h += __shfl_xor(s1h, 16); s1h += __shfl_xor(s1h, 32);
            s2h += __shfl_xor(s2h, 16); s2h += __shfl_xor(s2h, 32);
            s1i += __shfl_xor(s1i, 16); s1i += __shfl_xor(s1i, 32);
            s2i += __shfl_xor(s2i, 16); s2i += __shfl_xor(s2i, 32);
            if (quad == 0) {
                red_h[wave][nidx][0] = s1h; red_h[wave][nidx][1] = s2h;
                red_i[wave][nidx][0] = s1i; red_i[wave][nidx][1] = s2i;
            }
            __syncthreads();
            float th = 0.f, qh = 0.f, ti = 0.f, qi = 0.f;
#pragma unroll
            for (int w = 0; w < 4; ++w) {
                th += red_h[w][nidx][0]; qh += red_h[w][nidx][1];
                ti += red_i[w][nidx][0]; qi += red_i[w][nidx][1];
            }
            const float inv64 = 1.0f / 64.0f;
            float muh = th * inv64, vah = qh * inv64 - muh * muh;
            float mui = ti * inv64, vai = qi * inv64 - mui * mui;
            float rsh = rsqrtf(vah + 1e-5f), rsi = rsqrtf(vai + 1e-5f);
#pragma unroll
            for (int r = 0; r < 4; ++r) {
                float sv = ghh * (acc_h[r] - muh) * rsh + bthh
                         + gih * (acc_i[r] - mui) * rsi + btih + bb;
                st_s[wave][quad * 4 + r][nidx] = sv;
            }
            __syncthreads();

            // ---- gates, c update, BN(c), h update (1 element/lane) ----
            float fv = st_s[wave][mc][jc];
            float iv = st_s[wave][mc][4 + jc];
            float ov = st_s[wave][mc][8 + jc];
            float gv = st_s[wave][mc][12 + jc];
            float c_old = cf[m_cg * HID + j_g];
            float c1 = sigmoidf_(fv) * c_old + sigmoidf_(iv) * tanhf_(gv);

            float cs = c1, cq = c1 * c1;
            cs += __shfl_xor(cs, 1); cs += __shfl_xor(cs, 2);
            cs += __shfl_xor(cs, 4); cs += __shfl_xor(cs, 8);
            cq += __shfl_xor(cq, 1); cq += __shfl_xor(cq, 2);
            cq += __shfl_xor(cq, 4); cq += __shfl_xor(cq, 8);
            if (mc == 0) { red_c[wave][jc][0] = cs; red_c[wave][jc][1] = cq; }
            __syncthreads();
            float tc = 0.f, qc = 0.f;
#pragma unroll
            for (int w = 0; w < 4; ++w) { tc += red_c[w][jc][0]; qc += red_c[w][jc][1]; }
            float muc = tc * inv64, vac = qc * inv64 - muc * muc;
            float bnc = gc * (c1 - muc) * rsqrtf(vac + 1e-5f) + btc;
            float h1 = sigmoidf_(ov) * tanhf_(bnc);

            float h_old = hf[m_cg * HID + j_g];
            bool mk = (t < len_c);
            float hN = mk ? h1 : h_old;
            float cN = mk ? c1 : c_old;
            hf[m_cg * HID + j_g] = hN;
            cf[m_cg * HID + j_g] = cN;
            hb[m_cg * HID + j_g] = f2bf(hN);
            if (layer == 0) y0b[(size_t)(t * BATCH + m_cg) * HID + j_g] = f2bf(hN);
            else            out[(size_t)(t * BATCH + m_cg) * HID + j_g] = hN;

            grid_barrier(bar_cnt, bar_gen);
        }

        // final h_n / c_n for this layer (block-local columns)
        {
            const size_t ybase = (size_t)T_STEPS * BATCH * HID;
            int m = tid >> 2, j4 = tid & 3;
            int j = wg * 4 + j4;
            out[ybase + (size_t)layer * BATCH * HID + (size_t)m * HID + j] = hf[m * HID + j];
            out[ybase + (size_t)2 * BATCH * HID + (size_t)layer * BATCH * HID + (size_t)m * HID + j] = cf[m * HID + j];
        }
    }
}

// ---------------- launch ----------------
extern "C" void kernel_launch(void* const* d_in, const int* in_sizes, int n_in,
                              void* d_out, int out_size, void* d_ws, size_t ws_size,
                              hipStream_t stream)
{
    const float* x      = (const float*)d_in[0];
    const int*   length = (const int*)  d_in[1];
    const float* w_ih0  = (const float*)d_in[2];
    const float* w_hh0  = (const float*)d_in[3];
    const float* b0     = (const float*)d_in[4];
    const float* g_ih0  = (const float*)d_in[5];
    const float* bt_ih0 = (const float*)d_in[6];
    const float* g_hh0  = (const float*)d_in[7];
    const float* bt_hh0 = (const float*)d_in[8];
    const float* g_c0   = (const float*)d_in[9];
    const float* bt_c0  = (const float*)d_in[10];
    const float* w_ih1  = (const float*)d_in[11];
    const float* w_hh1  = (const float*)d_in[12];
    const float* b1     = (const float*)d_in[13];
    const float* g_ih1  = (const float*)d_in[14];
    const float* bt_ih1 = (const float*)d_in[15];
    const float* g_hh1  = (const float*)d_in[16];
    const float* bt_hh1 = (const float*)d_in[17];
    const float* g_c1   = (const float*)d_in[18];
    const float* bt_c1  = (const float*)d_in[19];

    char* ws = (char*)d_ws;
    // workspace layout (all 256B aligned)
    unsigned* bar_cnt = (unsigned*)(ws + 0);
    unsigned* bar_gen = (unsigned*)(ws + 128);
    float* h0f = (float*)(ws + 256);
    float* c0f = (float*)(ws + 262400);
    float* h1f = (float*)(ws + 524544);
    float* c1f = (float*)(ws + 786688);
    short* h0b = (short*)(ws + 1048832);
    short* h1b = (short*)(ws + 1179904);
    short* xb    = (short*)(ws + 1310976);
    short* y0b   = (short*)(ws + 18088192);
    short* wih0T = (short*)(ws + 51642624);
    short* whh0T = (short*)(ws + 55836928);
    short* wih1T = (short*)(ws + 64225536);
    short* whh1T = (short*)(ws + 72614144);
    // total footprint: 81,002,752 bytes

    // zero barrier + h/c state (re-poisoned 0xAA before each timed launch)
    hipMemsetAsync(ws, 0, 1310976, stream);

    cvt_bf16_kernel<<<2048, 256, 0, stream>>>(x, xb, T_STEPS * BATCH * DIN);

    dim3 tb(32, 8);
    transpose_bf16_kernel<<<dim3(NCOLS / 32, DIN / 32), tb, 0, stream>>>(w_ih0, wih0T, DIN, NCOLS);
    transpose_bf16_kernel<<<dim3(NCOLS / 32, HID / 32), tb, 0, stream>>>(w_hh0, whh0T, HID, NCOLS);
    transpose_bf16_kernel<<<dim3(NCOLS / 32, HID / 32), tb, 0, stream>>>(w_ih1, wih1T, HID, NCOLS);
    transpose_bf16_kernel<<<dim3(NCOLS / 32, HID / 32), tb, 0, stream>>>(w_hh1, whh1T, HID, NCOLS);

    lstm_persist<<<NBLK, TPB, 0, stream>>>(
        length,
        b0, g_ih0, bt_ih0, g_hh0, bt_hh0, g_c0, bt_c0,
        b1, g_ih1, bt_ih1, g_hh1, bt_hh1, g_c1, bt_c1,
        xb, y0b, wih0T, whh0T, wih1T, whh1T,
        h0f, c0f, h1f, c1f, h0b, h1b,
        bar_cnt, bar_gen,
        (float*)d_out);
}

// Round 3
// 10491.296 us; speedup vs baseline: 2.7495x; 2.7495x over previous
//
#include <hip/hip_runtime.h>

// ---------------- problem constants ----------------
#define T_STEPS 256
#define BATCH   64
#define DIN     512
#define HID     1024
#define NCOLS   4096   // 4*HID
#define NBLK    256    // persistent blocks (1 per CU)
#define TPB     256    // 4 waves

typedef __attribute__((ext_vector_type(8))) short short8;
typedef __attribute__((ext_vector_type(4))) float float4v;

__device__ __forceinline__ short f2bf(float x) {
    unsigned u = __float_as_uint(x);
    u += 0x7FFFu + ((u >> 16) & 1u);   // RNE
    return (short)(u >> 16);
}
__device__ __forceinline__ float sigmoidf_(float x) { return 1.0f / (1.0f + __expf(-x)); }
__device__ __forceinline__ float tanhf_(float x)    { return 1.0f - 2.0f / (__expf(2.0f * x) + 1.0f); }

// ---------------- prologue kernels ----------------
__global__ void cvt_bf16_kernel(const float* __restrict__ src, short* __restrict__ dst, int n) {
    int i = blockIdx.x * blockDim.x + threadIdx.x;
    int stride = gridDim.x * blockDim.x;
    for (; i < n; i += stride) dst[i] = f2bf(src[i]);
}

// src: R x C fp32 row-major -> dst: C x R bf16 row-major
__global__ void transpose_bf16_kernel(const float* __restrict__ src, short* __restrict__ dst,
                                      int R, int C) {
    __shared__ float tile[32][33];
    int tx = threadIdx.x, ty = threadIdx.y;
    int r0 = blockIdx.y * 32, c0 = blockIdx.x * 32;
#pragma unroll
    for (int i = 0; i < 32; i += 8)
        tile[ty + i][tx] = src[(size_t)(r0 + ty + i) * C + (c0 + tx)];
    __syncthreads();
#pragma unroll
    for (int i = 0; i < 32; i += 8)
        dst[(size_t)(c0 + ty + i) * R + (r0 + tx)] = f2bf(tile[tx][ty + i]);
}

// ---------------- fused persistent LSTM ----------------
// Block wg owns H-columns [wg*4, wg*4+4) -> s-columns {wg*4+jj + g*1024}.
// wave w computes batch rows [16w,16w+16). MFMA 16x16x32 bf16:
//   A-frag: lane holds A[m=lane&15][k=quad*8+j]  (8 contiguous bf16)
//   B-frag: lane holds B[k=quad*8+j][n=lane&15]
//   D:      lane holds D[row=quad*4+r][col=lane&15], r=0..3
//
// Grid sync: RMW-free flag barrier. Every block release-stores a monotonic
// epoch to flags[wg] (64B-padded). Block 0's 256 threads relaxed-poll one flag
// each (relaxed loads reach the coherence point, no cache-inv per poll), then
// one acquire fence + release-store of gen. Other blocks relaxed-poll gen,
// then one acquire fence. Weights live in VGPRs (1 block/CU -> 512 VGPR
// budget), so per-step invalidations cannot evict them.
__global__ __launch_bounds__(TPB, 1) void lstm_persist(
    const int* __restrict__ length,
    const float* __restrict__ b0,  const float* __restrict__ g_ih0, const float* __restrict__ bt_ih0,
    const float* __restrict__ g_hh0, const float* __restrict__ bt_hh0,
    const float* __restrict__ g_c0,  const float* __restrict__ bt_c0,
    const float* __restrict__ b1,  const float* __restrict__ g_ih1, const float* __restrict__ bt_ih1,
    const float* __restrict__ g_hh1, const float* __restrict__ bt_hh1,
    const float* __restrict__ g_c1,  const float* __restrict__ bt_c1,
    const short* __restrict__ xb, short* __restrict__ y0b,
    const short* __restrict__ wih0T, const short* __restrict__ whh0T,
    const short* __restrict__ wih1T, const short* __restrict__ whh1T,
    short* __restrict__ h0b, short* __restrict__ h1b,
    unsigned* __restrict__ gen, unsigned* __restrict__ flags,
    float* __restrict__ out)
{
    const int wg   = blockIdx.x;
    const int tid  = threadIdx.x;
    const int wave = tid >> 6;
    const int lane = tid & 63;
    const int nidx = lane & 15;
    const int quad = lane >> 4;

    __shared__ float st_s[4][16][17];   // per-wave 16x16 s tile (+pad)
    __shared__ float red_h[4][16][2];   // per-wave column (sum,sumsq) for h@Whh
    __shared__ float red_i[4][16][2];   // ... for x@Wih
    __shared__ float red_c[4][4][2];    // per-wave (sum,sumsq) for c1, 4 j's

    const int jj   = nidx & 3;
    const int gidx = nidx >> 2;
    const int ncol = wg * 4 + jj + gidx * HID;   // s-space column 0..4095
    const int m_row = wave * 16 + nidx;          // A-fragment batch row

    const int mc   = lane & 15;                  // c-phase: row within wave
    const int jc   = quad;                       // c-phase: which of 4 j's
    const int m_cg = wave * 16 + mc;
    const int j_g  = wg * 4 + jc;
    const int len_c = length[m_cg];
    const float inv64 = 1.0f / 64.0f;

#pragma unroll
    for (int layer = 0; layer < 2; ++layer) {
        const int K  = layer ? HID : DIN;
        const int KI = K >> 5;
        const short* xin  = layer ? y0b   : xb;
        const short* wTih = layer ? wih1T : wih0T;
        const short* wThh = layer ? whh1T : whh0T;
        short* hb = layer ? h1b : h0b;

        const float gih  = (layer ? g_ih1  : g_ih0 )[ncol];
        const float btih = (layer ? bt_ih1 : bt_ih0)[ncol];
        const float ghh  = (layer ? g_hh1  : g_hh0)[ncol];
        const float bthh = (layer ? bt_hh1 : bt_hh0)[ncol];
        const float bb   = (layer ? b1     : b0   )[ncol];
        const float gc   = (layer ? g_c1   : g_c0 )[j_g];
        const float btc  = (layer ? bt_c1  : bt_c0)[j_g];

        // ---- load this wave's B fragments into registers (once per layer) ----
        short8 Bh[32];
        const short8* bhp = (const short8*)wThh + (((size_t)ncol * HID) >> 3) + quad;
#pragma unroll
        for (int kk = 0; kk < 32; ++kk) Bh[kk] = bhp[kk * 4];
        short8 Bi[32];
        const short8* bip = (const short8*)wTih + (((size_t)ncol * K) >> 3) + quad;
#pragma unroll
        for (int kk = 0; kk < 32; ++kk) if (kk < KI) Bi[kk] = bip[kk * 4];

        float h_st = 0.f, c_st = 0.f;    // this thread's (m_cg, j_g) state

#pragma unroll 1
        for (int t = 0; t < T_STEPS; ++t) {
            // ---- ih GEMM: inputs already available, hides in barrier wait ----
            const short8* Axp = (const short8*)xin + (((size_t)(t * BATCH + m_row) * K) >> 3) + quad;
            float4v acc_i = {0.f, 0.f, 0.f, 0.f};
#pragma unroll
            for (int kk = 0; kk < 32; ++kk)
                if (kk < KI)
                    acc_i = __builtin_amdgcn_mfma_f32_16x16x32_bf16(Axp[kk * 4], Bi[kk], acc_i, 0, 0, 0);

            // ---- grid wait: h(t-1) must be visible ----
            const unsigned need = (unsigned)(layer * T_STEPS + t);
            if (need > 0u) {
                if (wg == 0) {
                    // aggregate: thread tid watches block tid's flag
                    while (__hip_atomic_load(&flags[tid * 16], __ATOMIC_RELAXED,
                                             __HIP_MEMORY_SCOPE_AGENT) < need)
                        __builtin_amdgcn_s_sleep(1);
                    __syncthreads();
                    if (tid == 0) {
                        __builtin_amdgcn_fence(__ATOMIC_ACQUIRE, "agent");
                        __hip_atomic_store(gen, need, __ATOMIC_RELEASE, __HIP_MEMORY_SCOPE_AGENT);
                    }
                    __syncthreads();
                } else {
                    if (tid == 0) {
                        while (__hip_atomic_load(gen, __ATOMIC_RELAXED,
                                                 __HIP_MEMORY_SCOPE_AGENT) < need)
                            __builtin_amdgcn_s_sleep(1);
                        __builtin_amdgcn_fence(__ATOMIC_ACQUIRE, "agent");
                    }
                    __syncthreads();
                }
            }

            // ---- hh GEMM on fresh h(t-1) ----
            const short8* Ahp = (const short8*)hb + (((size_t)m_row * HID) >> 3) + quad;
            float4v acc_h = {0.f, 0.f, 0.f, 0.f};
#pragma unroll
            for (int kk = 0; kk < 32; ++kk)
                acc_h = __builtin_amdgcn_mfma_f32_16x16x32_bf16(Ahp[kk * 4], Bh[kk], acc_h, 0, 0, 0);

            // ---- per-column batch stats (biased var over 64 rows) ----
            float s1h = acc_h[0] + acc_h[1] + acc_h[2] + acc_h[3];
            float s2h = acc_h[0]*acc_h[0] + acc_h[1]*acc_h[1] + acc_h[2]*acc_h[2] + acc_h[3]*acc_h[3];
            float s1i = acc_i[0] + acc_i[1] + acc_i[2] + acc_i[3];
            float s2i = acc_i[0]*acc_i[0] + acc_i[1]*acc_i[1] + acc_i[2]*acc_i[2] + acc_i[3]*acc_i[3];
            s1h += __shfl_xor(s1h, 16); s1h += __shfl_xor(s1h, 32);
            s2h += __shfl_xor(s2h, 16); s2h += __shfl_xor(s2h, 32);
            s1i += __shfl_xor(s1i, 16); s1i += __shfl_xor(s1i, 32);
            s2i += __shfl_xor(s2i, 16); s2i += __shfl_xor(s2i, 32);
            if (quad == 0) {
                red_h[wave][nidx][0] = s1h; red_h[wave][nidx][1] = s2h;
                red_i[wave][nidx][0] = s1i; red_i[wave][nidx][1] = s2i;
            }
            __syncthreads();
            float th = 0.f, qh = 0.f, ti = 0.f, qi = 0.f;
#pragma unroll
            for (int w = 0; w < 4; ++w) {
                th += red_h[w][nidx][0]; qh += red_h[w][nidx][1];
                ti += red_i[w][nidx][0]; qi += red_i[w][nidx][1];
            }
            float muh = th * inv64, vah = qh * inv64 - muh * muh;
            float mui = ti * inv64, vai = qi * inv64 - mui * mui;
            float rsh = rsqrtf(vah + 1e-5f), rsi = rsqrtf(vai + 1e-5f);
#pragma unroll
            for (int r = 0; r < 4; ++r) {
                float sv = ghh * (acc_h[r] - muh) * rsh + bthh
                         + gih * (acc_i[r] - mui) * rsi + btih + bb;
                st_s[wave][quad * 4 + r][nidx] = sv;
            }
            __syncthreads();

            // ---- gates, c update, BN(c), h update (1 element/lane) ----
            float fv = st_s[wave][mc][jc];
            float iv = st_s[wave][mc][4 + jc];
            float ov = st_s[wave][mc][8 + jc];
            float gv = st_s[wave][mc][12 + jc];
            float c1 = sigmoidf_(fv) * c_st + sigmoidf_(iv) * tanhf_(gv);

            float cs = c1, cq = c1 * c1;
            cs += __shfl_xor(cs, 1); cs += __shfl_xor(cs, 2);
            cs += __shfl_xor(cs, 4); cs += __shfl_xor(cs, 8);
            cq += __shfl_xor(cq, 1); cq += __shfl_xor(cq, 2);
            cq += __shfl_xor(cq, 4); cq += __shfl_xor(cq, 8);
            if (mc == 0) { red_c[wave][jc][0] = cs; red_c[wave][jc][1] = cq; }
            __syncthreads();
            float tc = 0.f, qc = 0.f;
#pragma unroll
            for (int w = 0; w < 4; ++w) { tc += red_c[w][jc][0]; qc += red_c[w][jc][1]; }
            float muc = tc * inv64, vac = qc * inv64 - muc * muc;
            float bnc = gc * (c1 - muc) * rsqrtf(vac + 1e-5f) + btc;
            float h1 = sigmoidf_(ov) * tanhf_(bnc);

            bool mk = (t < len_c);
            h_st = mk ? h1 : h_st;
            c_st = mk ? c1 : c_st;

            hb[m_cg * HID + j_g] = f2bf(h_st);
            if (layer == 0) y0b[(size_t)(t * BATCH + m_cg) * HID + j_g] = f2bf(h_st);
            else            out[(size_t)(t * BATCH + m_cg) * HID + j_g] = h_st;

            // ---- arrive: epoch need+1 ----
            __syncthreads();   // drains this block's stores (waitcnt before s_barrier)
            if (tid == 0)
                __hip_atomic_store(&flags[wg * 16], need + 1u, __ATOMIC_RELEASE,
                                   __HIP_MEMORY_SCOPE_AGENT);
        }

        // final h_n / c_n for this layer, straight from registers
        {
            const size_t ybase = (size_t)T_STEPS * BATCH * HID;
            out[ybase + (size_t)layer * BATCH * HID + (size_t)m_cg * HID + j_g] = h_st;
            out[ybase + (size_t)(2 + layer) * BATCH * HID + (size_t)m_cg * HID + j_g] = c_st;
        }
    }
}

// ---------------- launch ----------------
extern "C" void kernel_launch(void* const* d_in, const int* in_sizes, int n_in,
                              void* d_out, int out_size, void* d_ws, size_t ws_size,
                              hipStream_t stream)
{
    const float* x      = (const float*)d_in[0];
    const int*   length = (const int*)  d_in[1];
    const float* w_ih0  = (const float*)d_in[2];
    const float* w_hh0  = (const float*)d_in[3];
    const float* b0     = (const float*)d_in[4];
    const float* g_ih0  = (const float*)d_in[5];
    const float* bt_ih0 = (const float*)d_in[6];
    const float* g_hh0  = (const float*)d_in[7];
    const float* bt_hh0 = (const float*)d_in[8];
    const float* g_c0   = (const float*)d_in[9];
    const float* bt_c0  = (const float*)d_in[10];
    const float* w_ih1  = (const float*)d_in[11];
    const float* w_hh1  = (const float*)d_in[12];
    const float* b1     = (const float*)d_in[13];
    const float* g_ih1  = (const float*)d_in[14];
    const float* bt_ih1 = (const float*)d_in[15];
    const float* g_hh1  = (const float*)d_in[16];
    const float* bt_hh1 = (const float*)d_in[17];
    const float* g_c1   = (const float*)d_in[18];
    const float* bt_c1  = (const float*)d_in[19];

    char* ws = (char*)d_ws;
    // workspace layout (16B-aligned throughout)
    unsigned* gen   = (unsigned*)(ws + 0);
    unsigned* flags = (unsigned*)(ws + 128);        // 256 flags, 64B stride
    short* h0b   = (short*)(ws + 16640);            // 131072 B
    short* h1b   = (short*)(ws + 147712);           // 131072 B
    short* xb    = (short*)(ws + 278784);           // 16777216 B
    short* y0b   = (short*)(ws + 17056000);         // 33554432 B
    short* wih0T = (short*)(ws + 50610432);         // 4194304 B
    short* whh0T = (short*)(ws + 54804736);         // 8388608 B
    short* wih1T = (short*)(ws + 63193344);         // 8388608 B
    short* whh1T = (short*)(ws + 71581952);         // 8388608 B
    // total footprint: 79,970,560 bytes

    // zero barrier state + initial h (re-poisoned 0xAA before each timed launch)
    (void)hipMemsetAsync(ws, 0, 278784, stream);

    cvt_bf16_kernel<<<2048, 256, 0, stream>>>(x, xb, T_STEPS * BATCH * DIN);

    dim3 tb(32, 8);
    transpose_bf16_kernel<<<dim3(NCOLS / 32, DIN / 32), tb, 0, stream>>>(w_ih0, wih0T, DIN, NCOLS);
    transpose_bf16_kernel<<<dim3(NCOLS / 32, HID / 32), tb, 0, stream>>>(w_hh0, whh0T, HID, NCOLS);
    transpose_bf16_kernel<<<dim3(NCOLS / 32, HID / 32), tb, 0, stream>>>(w_ih1, wih1T, HID, NCOLS);
    transpose_bf16_kernel<<<dim3(NCOLS / 32, HID / 32), tb, 0, stream>>>(w_hh1, whh1T, HID, NCOLS);

    lstm_persist<<<NBLK, TPB, 0, stream>>>(
        length,
        b0, g_ih0, bt_ih0, g_hh0, bt_hh0, g_c0, bt_c0,
        b1, g_ih1, bt_ih1, g_hh1, bt_hh1, g_c1, bt_c1,
        xb, y0b, wih0T, whh0T, wih1T, whh1T,
        h0b, h1b,
        gen, flags,
        (float*)d_out);
}

// Round 4
// 7307.496 us; speedup vs baseline: 3.9475x; 1.4357x over previous
//
#include <hip/hip_runtime.h>

// ---------------- problem constants ----------------
#define T_STEPS 256
#define BATCH   64
#define DIN     512
#define HID     1024
#define NCOLS   4096   // 4*HID
#define NBLK    256    // persistent blocks (1 per CU)
#define TPB     256    // 4 waves

typedef __attribute__((ext_vector_type(8))) short short8;
typedef __attribute__((ext_vector_type(4))) float float4v;
typedef unsigned long long u64;

union Frag { u64 u[2]; short8 s; };

__device__ __forceinline__ short f2bf(float x) {
    unsigned u = __float_as_uint(x);
    u += 0x7FFFu + ((u >> 16) & 1u);   // RNE
    return (short)(u >> 16);
}
__device__ __forceinline__ float sigmoidf_(float x) { return 1.0f / (1.0f + __expf(-x)); }
__device__ __forceinline__ float tanhf_(float x)    { return 1.0f - 2.0f / (__expf(2.0f * x) + 1.0f); }

// ---------------- prologue kernels ----------------
__global__ void cvt_bf16_kernel(const float* __restrict__ src, short* __restrict__ dst, int n) {
    int i = blockIdx.x * blockDim.x + threadIdx.x;
    int stride = gridDim.x * blockDim.x;
    for (; i < n; i += stride) dst[i] = f2bf(src[i]);
}

// src: R x C fp32 row-major -> dst: C x R bf16 row-major
__global__ void transpose_bf16_kernel(const float* __restrict__ src, short* __restrict__ dst,
                                      int R, int C) {
    __shared__ float tile[32][33];
    int tx = threadIdx.x, ty = threadIdx.y;
    int r0 = blockIdx.y * 32, c0 = blockIdx.x * 32;
#pragma unroll
    for (int i = 0; i < 32; i += 8)
        tile[ty + i][tx] = src[(size_t)(r0 + ty + i) * C + (c0 + tx)];
    __syncthreads();
#pragma unroll
    for (int i = 0; i < 32; i += 8)
        dst[(size_t)(c0 + ty + i) * R + (r0 + tx)] = f2bf(tile[tx][ty + i]);
}

// ---------------- fused persistent LSTM ----------------
// Coherence design (gfx950, per-XCD non-coherent L2):
//  - ALL cross-block data (h buffers, y0 activations, flags) moves via
//    relaxed AGENT-scope atomic load/store => sc0 sc1 cache-bypass ops that
//    read/write the device coherence point. NO acquire/release fences in the
//    loop => no L1/L2 invalidates or wbl2 flushes (R3's 20us/step cost).
//  - Read-only data (x, W_ih) uses normal cached loads; with no
//    invalidations it stays L2-resident across all 512 steps.
//  - W_hh is pinned in VGPRs via atomic loads (cannot be rematerialized).
//  - Ordering: s_waitcnt(0) per thread + __syncthreads before the flag
//    store (release); control dependency after the poll (acquire).
//  - h double-buffered by t parity to kill the read/write race.
__global__ __launch_bounds__(TPB, 1) void lstm_persist(
    const int* __restrict__ length,
    const float* __restrict__ b0,  const float* __restrict__ g_ih0, const float* __restrict__ bt_ih0,
    const float* __restrict__ g_hh0, const float* __restrict__ bt_hh0,
    const float* __restrict__ g_c0,  const float* __restrict__ bt_c0,
    const float* __restrict__ b1,  const float* __restrict__ g_ih1, const float* __restrict__ bt_ih1,
    const float* __restrict__ g_hh1, const float* __restrict__ bt_hh1,
    const float* __restrict__ g_c1,  const float* __restrict__ bt_c1,
    const short* __restrict__ xb, short* __restrict__ y0b,
    const short* __restrict__ wih0T, const short* __restrict__ whh0T,
    const short* __restrict__ wih1T, const short* __restrict__ whh1T,
    short* __restrict__ h0A, short* __restrict__ h0B,
    short* __restrict__ h1A, short* __restrict__ h1B,
    unsigned* __restrict__ flags,
    float* __restrict__ out)
{
    const int wg   = blockIdx.x;
    const int tid  = threadIdx.x;
    const int wave = tid >> 6;
    const int lane = tid & 63;
    const int nidx = lane & 15;
    const int quad = lane >> 4;

    __shared__ float st_s[4][16][17];   // per-wave 16x16 s tile (+pad)
    __shared__ float red_h[4][16][2];   // per-wave column (sum,sumsq) for h@Whh
    __shared__ float red_i[4][16][2];   // ... for x@Wih
    __shared__ float red_c[4][4][2];    // per-wave (sum,sumsq) for c1, 4 j's
    __shared__ unsigned okv[4];         // barrier poll combine

    const int jj   = nidx & 3;
    const int gidx = nidx >> 2;
    const int ncol = wg * 4 + jj + gidx * HID;   // s-space column 0..4095
    const int m_row = wave * 16 + nidx;          // A-fragment batch row

    const int mc   = lane & 15;                  // c-phase: row within wave
    const int jc   = quad;                       // c-phase: which of 4 j's
    const int m_cg = wave * 16 + mc;
    const int j_g  = wg * 4 + jc;
    const int len_c = length[m_cg];
    const float inv64 = 1.0f / 64.0f;

#pragma unroll
    for (int layer = 0; layer < 2; ++layer) {
        const int K  = layer ? HID : DIN;
        const int KI = K >> 5;
        const short* xin  = layer ? y0b   : xb;
        const short* wTih = layer ? wih1T : wih0T;
        const short* wThh = layer ? whh1T : whh0T;
        short* hA = layer ? h1A : h0A;
        short* hB = layer ? h1B : h0B;

        const float gih  = (layer ? g_ih1  : g_ih0 )[ncol];
        const float btih = (layer ? bt_ih1 : bt_ih0)[ncol];
        const float ghh  = (layer ? g_hh1  : g_hh0)[ncol];
        const float bthh = (layer ? bt_hh1 : bt_hh0)[ncol];
        const float bb   = (layer ? b1     : b0   )[ncol];
        const float gc   = (layer ? g_c1   : g_c0 )[j_g];
        const float btc  = (layer ? bt_c1  : bt_c0)[j_g];

        // ---- pin W_hh fragments in VGPRs via atomic loads (non-sinkable) ----
        u64 Bh2[64];
        const u64* bhp = (const u64*)wThh + (size_t)ncol * (HID / 4) + quad * 2;
#pragma unroll
        for (int kk = 0; kk < 32; ++kk) {
            Bh2[2 * kk]     = __hip_atomic_load(bhp + kk * 8,     __ATOMIC_RELAXED, __HIP_MEMORY_SCOPE_AGENT);
            Bh2[2 * kk + 1] = __hip_atomic_load(bhp + kk * 8 + 1, __ATOMIC_RELAXED, __HIP_MEMORY_SCOPE_AGENT);
        }

        float h_st = 0.f, c_st = 0.f;    // this thread's (m_cg, j_g) state

#pragma unroll 1
        for (int t = 0; t < T_STEPS; ++t) {
            const short* hb_r = (t & 1) ? hB : hA;   // holds h(t-1)
            short*       hb_w = (t & 1) ? hA : hB;   // becomes h(t)

            // ---- ih GEMM (independent of h(t-1); normal cached loads) ----
            const short8* Axp = (const short8*)xin + (((size_t)(t * BATCH + m_row) * K) >> 3) + quad;
            const short8* Bip = (const short8*)wTih + (((size_t)ncol * K) >> 3) + quad;
            float4v ai0 = {0.f, 0.f, 0.f, 0.f}, ai1 = {0.f, 0.f, 0.f, 0.f};
#pragma unroll
            for (int kk = 0; kk < 32; ++kk) {
                if (kk < KI) {
                    if (kk & 1) ai1 = __builtin_amdgcn_mfma_f32_16x16x32_bf16(Axp[kk * 4], Bip[kk * 4], ai1, 0, 0, 0);
                    else        ai0 = __builtin_amdgcn_mfma_f32_16x16x32_bf16(Axp[kk * 4], Bip[kk * 4], ai0, 0, 0, 0);
                }
            }
            float4v acc_i = ai0 + ai1;

            // ---- grid wait: all flags >= need (one L3 round trip) ----
            const unsigned need = (unsigned)(layer * T_STEPS + t);
            if (need > 0u) {
                for (;;) {
                    unsigned f = __hip_atomic_load(&flags[tid * 4], __ATOMIC_RELAXED,
                                                   __HIP_MEMORY_SCOPE_AGENT);
                    unsigned long long bal = __ballot(f >= need);
                    if (lane == 0) okv[wave] = (bal + 1ull == 0ull);
                    __syncthreads();
                    bool all4 = okv[0] && okv[1] && okv[2] && okv[3];
                    __syncthreads();
                    if (all4) break;
                    __builtin_amdgcn_s_sleep(2);
                }
            }

            // ---- hh GEMM: A = h(t-1) via cache-bypass atomic loads ----
            u64 A2[64];
            const u64* hp = (const u64*)hb_r + (size_t)m_row * (HID / 4) + quad * 2;
#pragma unroll
            for (int kk = 0; kk < 32; ++kk) {
                A2[2 * kk]     = __hip_atomic_load(hp + kk * 8,     __ATOMIC_RELAXED, __HIP_MEMORY_SCOPE_AGENT);
                A2[2 * kk + 1] = __hip_atomic_load(hp + kk * 8 + 1, __ATOMIC_RELAXED, __HIP_MEMORY_SCOPE_AGENT);
            }
            float4v ah0 = {0.f,0.f,0.f,0.f}, ah1 = {0.f,0.f,0.f,0.f};
            float4v ah2 = {0.f,0.f,0.f,0.f}, ah3 = {0.f,0.f,0.f,0.f};
#pragma unroll
            for (int kk = 0; kk < 32; ++kk) {
                Frag fa, fb;
                fa.u[0] = A2[2 * kk];  fa.u[1] = A2[2 * kk + 1];
                fb.u[0] = Bh2[2 * kk]; fb.u[1] = Bh2[2 * kk + 1];
                switch (kk & 3) {
                    case 0: ah0 = __builtin_amdgcn_mfma_f32_16x16x32_bf16(fa.s, fb.s, ah0, 0, 0, 0); break;
                    case 1: ah1 = __builtin_amdgcn_mfma_f32_16x16x32_bf16(fa.s, fb.s, ah1, 0, 0, 0); break;
                    case 2: ah2 = __builtin_amdgcn_mfma_f32_16x16x32_bf16(fa.s, fb.s, ah2, 0, 0, 0); break;
                    default: ah3 = __builtin_amdgcn_mfma_f32_16x16x32_bf16(fa.s, fb.s, ah3, 0, 0, 0); break;
                }
            }
            float4v acc_h = (ah0 + ah1) + (ah2 + ah3);

            // ---- per-column batch stats (biased var over 64 rows) ----
            float s1h = acc_h[0] + acc_h[1] + acc_h[2] + acc_h[3];
            float s2h = acc_h[0]*acc_h[0] + acc_h[1]*acc_h[1] + acc_h[2]*acc_h[2] + acc_h[3]*acc_h[3];
            float s1i = acc_i[0] + acc_i[1] + acc_i[2] + acc_i[3];
            float s2i = acc_i[0]*acc_i[0] + acc_i[1]*acc_i[1] + acc_i[2]*acc_i[2] + acc_i[3]*acc_i[3];
            s1h += __shfl_xor(s1h, 16); s1h += __shfl_xor(s1h, 32);
            s2h += __shfl_xor(s2h, 16); s2h += __shfl_xor(s2h, 32);
            s1i += __shfl_xor(s1i, 16); s1i += __shfl_xor(s1i, 32);
            s2i += __shfl_xor(s2i, 16); s2i += __shfl_xor(s2i, 32);
            if (quad == 0) {
                red_h[wave][nidx][0] = s1h; red_h[wave][nidx][1] = s2h;
                red_i[wave][nidx][0] = s1i; red_i[wave][nidx][1] = s2i;
            }
            __syncthreads();
            float th = 0.f, qh = 0.f, ti = 0.f, qi = 0.f;
#pragma unroll
            for (int w = 0; w < 4; ++w) {
                th += red_h[w][nidx][0]; qh += red_h[w][nidx][1];
                ti += red_i[w][nidx][0]; qi += red_i[w][nidx][1];
            }
            float muh = th * inv64, vah = qh * inv64 - muh * muh;
            float mui = ti * inv64, vai = qi * inv64 - mui * mui;
            float rsh = rsqrtf(vah + 1e-5f), rsi = rsqrtf(vai + 1e-5f);
#pragma unroll
            for (int r = 0; r < 4; ++r) {
                float sv = ghh * (acc_h[r] - muh) * rsh + bthh
                         + gih * (acc_i[r] - mui) * rsi + btih + bb;
                st_s[wave][quad * 4 + r][nidx] = sv;
            }
            __syncthreads();

            // ---- gates, c update, BN(c), h update (1 element/lane) ----
            float fv = st_s[wave][mc][jc];
            float iv = st_s[wave][mc][4 + jc];
            float ov = st_s[wave][mc][8 + jc];
            float gv = st_s[wave][mc][12 + jc];
            float c1 = sigmoidf_(fv) * c_st + sigmoidf_(iv) * tanhf_(gv);

            float cs = c1, cq = c1 * c1;
            cs += __shfl_xor(cs, 1); cs += __shfl_xor(cs, 2);
            cs += __shfl_xor(cs, 4); cs += __shfl_xor(cs, 8);
            cq += __shfl_xor(cq, 1); cq += __shfl_xor(cq, 2);
            cq += __shfl_xor(cq, 4); cq += __shfl_xor(cq, 8);
            if (mc == 0) { red_c[wave][jc][0] = cs; red_c[wave][jc][1] = cq; }
            __syncthreads();
            float tc = 0.f, qc = 0.f;
#pragma unroll
            for (int w = 0; w < 4; ++w) { tc += red_c[w][jc][0]; qc += red_c[w][jc][1]; }
            float muc = tc * inv64, vac = qc * inv64 - muc * muc;
            float bnc = gc * (c1 - muc) * rsqrtf(vac + 1e-5f) + btc;
            float h1 = sigmoidf_(ov) * tanhf_(bnc);

            bool mk = (t < len_c);
            h_st = mk ? h1 : h_st;
            c_st = mk ? c1 : c_st;

            // ---- publish h(t) + activations via cache-bypass stores ----
            short hv = f2bf(h_st);
            __hip_atomic_store(&hb_w[m_cg * HID + j_g], hv, __ATOMIC_RELAXED, __HIP_MEMORY_SCOPE_AGENT);
            if (layer == 0)
                __hip_atomic_store(&y0b[(size_t)(t * BATCH + m_cg) * HID + j_g], hv,
                                   __ATOMIC_RELAXED, __HIP_MEMORY_SCOPE_AGENT);
            else
                out[(size_t)(t * BATCH + m_cg) * HID + j_g] = h_st;

            // ---- arrive: drain own stores, then flag (no wbl2, no inv) ----
            __builtin_amdgcn_s_waitcnt(0);
            __syncthreads();
            if (tid == 0)
                __hip_atomic_store(&flags[wg * 4], need + 1u, __ATOMIC_RELAXED,
                                   __HIP_MEMORY_SCOPE_AGENT);
        }

        // final h_n / c_n for this layer, straight from registers
        {
            const size_t ybase = (size_t)T_STEPS * BATCH * HID;
            out[ybase + (size_t)layer * BATCH * HID + (size_t)m_cg * HID + j_g] = h_st;
            out[ybase + (size_t)(2 + layer) * BATCH * HID + (size_t)m_cg * HID + j_g] = c_st;
        }
    }
}

// ---------------- launch ----------------
extern "C" void kernel_launch(void* const* d_in, const int* in_sizes, int n_in,
                              void* d_out, int out_size, void* d_ws, size_t ws_size,
                              hipStream_t stream)
{
    const float* x      = (const float*)d_in[0];
    const int*   length = (const int*)  d_in[1];
    const float* w_ih0  = (const float*)d_in[2];
    const float* w_hh0  = (const float*)d_in[3];
    const float* b0     = (const float*)d_in[4];
    const float* g_ih0  = (const float*)d_in[5];
    const float* bt_ih0 = (const float*)d_in[6];
    const float* g_hh0  = (const float*)d_in[7];
    const float* bt_hh0 = (const float*)d_in[8];
    const float* g_c0   = (const float*)d_in[9];
    const float* bt_c0  = (const float*)d_in[10];
    const float* w_ih1  = (const float*)d_in[11];
    const float* w_hh1  = (const float*)d_in[12];
    const float* b1     = (const float*)d_in[13];
    const float* g_ih1  = (const float*)d_in[14];
    const float* bt_ih1 = (const float*)d_in[15];
    const float* g_hh1  = (const float*)d_in[16];
    const float* bt_hh1 = (const float*)d_in[17];
    const float* g_c1   = (const float*)d_in[18];
    const float* bt_c1  = (const float*)d_in[19];

    char* ws = (char*)d_ws;
    // workspace layout (16B-aligned throughout)
    unsigned* flags = (unsigned*)(ws + 0);          // 256 flags, 16B stride = 4096 B
    short* h0A   = (short*)(ws + 4096);             // 131072 B
    short* h0B   = (short*)(ws + 135168);           // 131072 B
    short* h1A   = (short*)(ws + 266240);           // 131072 B
    short* h1B   = (short*)(ws + 397312);           // 131072 B
    // ---- end of zeroed region: 528384 ----
    short* xb    = (short*)(ws + 528384);           // 16777216 B
    short* y0b   = (short*)(ws + 17305600);         // 33554432 B
    short* wih0T = (short*)(ws + 50860032);         // 4194304 B
    short* whh0T = (short*)(ws + 55054336);         // 8388608 B
    short* wih1T = (short*)(ws + 63442944);         // 8388608 B
    short* whh1T = (short*)(ws + 71831552);         // 8388608 B
    // total footprint: 80,220,160 bytes

    // zero flags + h double-buffers (harness re-poisons ws each timed launch)
    (void)hipMemsetAsync(ws, 0, 528384, stream);

    cvt_bf16_kernel<<<2048, 256, 0, stream>>>(x, xb, T_STEPS * BATCH * DIN);

    dim3 tb(32, 8);
    transpose_bf16_kernel<<<dim3(NCOLS / 32, DIN / 32), tb, 0, stream>>>(w_ih0, wih0T, DIN, NCOLS);
    transpose_bf16_kernel<<<dim3(NCOLS / 32, HID / 32), tb, 0, stream>>>(w_hh0, whh0T, HID, NCOLS);
    transpose_bf16_kernel<<<dim3(NCOLS / 32, HID / 32), tb, 0, stream>>>(w_ih1, wih1T, HID, NCOLS);
    transpose_bf16_kernel<<<dim3(NCOLS / 32, HID / 32), tb, 0, stream>>>(w_hh1, whh1T, HID, NCOLS);

    lstm_persist<<<NBLK, TPB, 0, stream>>>(
        length,
        b0, g_ih0, bt_ih0, g_hh0, bt_hh0, g_c0, bt_c0,
        b1, g_ih1, bt_ih1, g_hh1, bt_hh1, g_c1, bt_c1,
        xb, y0b, wih0T, whh0T, wih1T, whh1T,
        h0A, h0B, h1A, h1B,
        flags,
        (float*)d_out);
}